// Round 2
// baseline (197651.379 us; speedup 1.0000x reference)
//
#include <hip/hip_runtime.h>

// NeuralODESIR round 2: precision-first. np reference is ~fp64; this ODE
// amplifies per-eval rounding ~3e4x (round-1 datum: fp32+fast_tanh -> 3.5e-2).
// So: all dot products + RK4 state in fp64 (v_fma_f64, half rate), activations
// tanhf on fp32-rounded pre-acts (~6e-8/act), weights pre-widened to fp64 in
// d_ws (W2 transposed for contiguous scalar loads). 1 thread = 1 trajectory.

#define NW1  (5 * 64)
#define NB1  64
#define NW2  (64 * 128)
#define NB2  128
#define NW3  (128 * 64)
#define NB3  64
#define NW4  (64 * 3)
#define NB4  3

// offsets (in doubles) inside d_ws
#define oW1  0
#define oB1  (oW1 + NW1)       // 320
#define oW2T (oB1 + NB1)       // 384
#define oB2  (oW2T + NW2)      // 8576
#define oW3  (oB2 + NB2)       // 8704
#define oB3  (oW3 + NW3)       // 16896
#define oW4  (oB3 + NB3)       // 16960
#define oB4  (oW4 + NW4)       // 17152
#define NTOT (oB4 + NB4)       // 17155

__device__ __forceinline__ void store_softmax(float* __restrict__ out, size_t base,
                                              float a, float b, float c) {
    float m  = fmaxf(a, fmaxf(b, c));
    float e0 = expf(a - m);
    float e1 = expf(b - m);
    float e2 = expf(c - m);
    float s  = e0 + e1 + e2;
    out[base + 0] = e0 / s;
    out[base + 1] = e1 / s;
    out[base + 2] = e2 / s;
}

// WD=true: weights are fp64 in ws (W2 transposed [128][64]).
// WD=false: fallback, fp32 original pointers (W2 original [64][128], strided).
template <typename WT, bool TW>
__device__ __forceinline__ void mlp_eval(
    double zs, double zi, double zr, double be, double ga,
    const WT* __restrict__ W1, const WT* __restrict__ b1,
    const WT* __restrict__ W2, const WT* __restrict__ b2,
    const WT* __restrict__ W3, const WT* __restrict__ b3,
    const WT* __restrict__ W4, const WT* __restrict__ b4,
    double& d0, double& d1, double& d2)
{
    float h1[64];
    // layer 1: 5 -> 64 (fp64 dot, fp32 tanh)
    #pragma unroll
    for (int j = 0; j < 64; ++j) {
        double t = (double)b1[j];
        t = fma((double)W1[0 * 64 + j], zs, t);
        t = fma((double)W1[1 * 64 + j], zi, t);
        t = fma((double)W1[2 * 64 + j], zr, t);
        t = fma((double)W1[3 * 64 + j], be, t);
        t = fma((double)W1[4 * 64 + j], ga, t);
        h1[j] = tanhf((float)t);
    }

    // layers 2+3 fused: 64 -> 128 -> 64, all accumulation fp64
    double acc[64];
    #pragma unroll
    for (int j = 0; j < 64; ++j) acc[j] = (double)b3[j];

    #pragma unroll 1
    for (int k = 0; k < 128; ++k) {
        double t = (double)b2[k];
        if (TW) {
            const WT* w2k = W2 + k * 64;       // contiguous row of W2^T
            #pragma unroll
            for (int i = 0; i < 64; ++i) t = fma((double)w2k[i], (double)h1[i], t);
        } else {
            const WT* w2k = W2 + k;            // strided column of W2
            #pragma unroll
            for (int i = 0; i < 64; ++i) t = fma((double)w2k[i * 128], (double)h1[i], t);
        }
        double td = (double)tanhf((float)t);
        const WT* w3k = W3 + k * 64;           // contiguous row of W3
        #pragma unroll
        for (int j = 0; j < 64; ++j) acc[j] = fma((double)w3k[j], td, acc[j]);
    }

    // layer 4: 64 -> 3 (fp64)
    double e0 = (double)b4[0], e1 = (double)b4[1], e2 = (double)b4[2];
    #pragma unroll
    for (int j = 0; j < 64; ++j) {
        double h = (double)tanhf((float)acc[j]);
        e0 = fma((double)W4[j * 3 + 0], h, e0);
        e1 = fma((double)W4[j * 3 + 1], h, e1);
        e2 = fma((double)W4[j * 3 + 2], h, e2);
    }
    d0 = e0; d1 = e1; d2 = e2;
}

template <typename WT, bool TW>
__global__ __launch_bounds__(256, 2) void sir_rk4_kernel(
    const float* __restrict__ y0,   const float* __restrict__ tspan,
    const float* __restrict__ beta, const float* __restrict__ gamma,
    const WT* __restrict__ W1,   const WT* __restrict__ b1,
    const WT* __restrict__ W2,   const WT* __restrict__ b2,
    const WT* __restrict__ W3,   const WT* __restrict__ b3,
    const WT* __restrict__ W4,   const WT* __restrict__ b4,
    float* __restrict__ out, int B, int T)
{
    int b = blockIdx.x * blockDim.x + threadIdx.x;
    if (b >= B) return;

    double ys = (double)y0[b * 3 + 0];
    double yi = (double)y0[b * 3 + 1];
    double yr = (double)y0[b * 3 + 2];
    double be = (double)beta[b];
    double ga = (double)gamma[b];

    // t = 0 row
    store_softmax(out, (size_t)b * 3, (float)ys, (float)yi, (float)yr);

    #pragma unroll 1
    for (int t = 0; t < T - 1; ++t) {
        double dt = (double)tspan[t + 1] - (double)tspan[t];

        double ks0 = 0.0, ks1 = 0.0, ks2 = 0.0;   // weighted k sum
        double zs = ys, zi = yi, zr = yr;          // stage input

        #pragma unroll 1
        for (int st = 0; st < 4; ++st) {
            double d0, d1, d2;
            mlp_eval<WT, TW>(zs, zi, zr, be, ga,
                             W1, b1, W2, b2, W3, b3, W4, b4, d0, d1, d2);
            double w = (st == 1 || st == 2) ? 2.0 : 1.0;
            ks0 = fma(w, d0, ks0);
            ks1 = fma(w, d1, ks1);
            ks2 = fma(w, d2, ks2);
            double a = (st < 2) ? 0.5 * dt : dt;   // input scale for next stage
            zs = fma(a, d0, ys);
            zi = fma(a, d1, yi);
            zr = fma(a, d2, yr);
        }

        double c = dt * (1.0 / 6.0);
        ys = fma(c, ks0, ys);
        yi = fma(c, ks1, yi);
        yr = fma(c, ks2, yr);

        store_softmax(out, ((size_t)(t + 1) * B + b) * 3, (float)ys, (float)yi, (float)yr);
    }
}

// widen all params to fp64 in ws; W2 transposed to [128][64]
__global__ void stage_params_kernel(
    const float* __restrict__ W1, const float* __restrict__ b1,
    const float* __restrict__ W2, const float* __restrict__ b2,
    const float* __restrict__ W3, const float* __restrict__ b3,
    const float* __restrict__ W4, const float* __restrict__ b4,
    double* __restrict__ P)
{
    int idx = blockIdx.x * blockDim.x + threadIdx.x;
    if (idx >= NTOT) return;
    float v;
    if (idx < oB1)       v = W1[idx - oW1];
    else if (idx < oW2T) v = b1[idx - oB1];
    else if (idx < oB2)  { int u = idx - oW2T; int k = u / 64; int i = u % 64; v = W2[i * 128 + k]; }
    else if (idx < oW3)  v = b2[idx - oB2];
    else if (idx < oB3)  v = W3[idx - oW3];
    else if (idx < oW4)  v = b3[idx - oB3];
    else if (idx < oB4)  v = W4[idx - oW4];
    else                 v = b4[idx - oB4];
    P[idx] = (double)v;
}

extern "C" void kernel_launch(void* const* d_in, const int* in_sizes, int n_in,
                              void* d_out, int out_size, void* d_ws, size_t ws_size,
                              hipStream_t stream) {
    const float* y0    = (const float*)d_in[0];
    const float* tspan = (const float*)d_in[1];
    const float* beta  = (const float*)d_in[2];
    const float* gamma = (const float*)d_in[3];
    const float* W1    = (const float*)d_in[4];
    const float* b1    = (const float*)d_in[5];
    const float* W2    = (const float*)d_in[6];
    const float* b2    = (const float*)d_in[7];
    const float* W3    = (const float*)d_in[8];
    const float* b3    = (const float*)d_in[9];
    const float* W4    = (const float*)d_in[10];
    const float* b4    = (const float*)d_in[11];

    int B = in_sizes[0] / 3;
    int T = in_sizes[1];
    float* out = (float*)d_out;

    int blocks = (B + 255) / 256;

    if (ws_size >= (size_t)NTOT * sizeof(double)) {
        double* P = (double*)d_ws;
        stage_params_kernel<<<(NTOT + 255) / 256, 256, 0, stream>>>(
            W1, b1, W2, b2, W3, b3, W4, b4, P);
        sir_rk4_kernel<double, true><<<blocks, 256, 0, stream>>>(
            y0, tspan, beta, gamma,
            P + oW1, P + oB1, P + oW2T, P + oB2,
            P + oW3, P + oB3, P + oW4,  P + oB4, out, B, T);
    } else {
        sir_rk4_kernel<float, false><<<blocks, 256, 0, stream>>>(
            y0, tspan, beta, gamma, W1, b1, W2, b2, W3, b3, W4, b4, out, B, T);
    }
}

// Round 3
// 192606.531 us; speedup vs baseline: 1.0262x; 1.0262x over previous
//
#include <hip/hip_runtime.h>

// NeuralODESIR round 3: full-fp64 datapath + custom fp64 tanh.
// Round-2 datum: fp64 dots + fp32 tanhf -> absmax 0.0195 (threshold 0.02);
// the fp32 rounding of 256 activations/eval (~5e-8) is amplified ~4e5x by the
// ODE. Fix: tanh computed AND carried in fp64 (deg-9 exp2 Taylor, rel ~7e-12).
// Perf fix: 4-way split dot chains + unroll-2 k-loop for ILP; 1 wave/SIMD
// (VGPR ~300) is fine since total work is only 8 waves/CU anyway.

#define NW1  (5 * 64)
#define NB1  64
#define NW2  (64 * 128)
#define NB2  128
#define NW3  (128 * 64)
#define NB3  64
#define NW4  (64 * 3)
#define NB4  3

// offsets (in doubles) inside d_ws
#define oW1  0
#define oB1  (oW1 + NW1)       // 320
#define oW2T (oB1 + NB1)       // 384
#define oB2  (oW2T + NW2)      // 8576
#define oW3  (oB2 + NB2)       // 8704
#define oB3  (oW3 + NW3)       // 16896
#define oW4  (oB3 + NB3)       // 16960
#define oB4  (oW4 + NW4)       // 17152
#define NTOT (oB4 + NB4)       // 17155

// fp64 tanh, |abs err| ~ 1e-12. tanh(x) = sign(x) * (1 - 2/(exp(2|x|)+1)).
// exp(2|x|) = 2^n * 2^f, f in [-0.5, 0.5]; 2^f via degree-9 Taylor of e^{f ln2}
// (rel err ~7e-12); division via fp32 rcp seed + 2 fp64 Newton refinements.
__device__ __forceinline__ double tanh64(double x) {
    const double TWO_LOG2E = 2.885390081777926814; // 2*log2(e)
    double ax = fabs(x);
    ax = fmin(ax, 20.0);                 // tanh(20) == 1.0 to 8.5e-18 < 0.5 ulp
    double u = ax * TWO_LOG2E;           // [0, 57.71]
    double n = rint(u);
    double f = u - n;                    // exact (Sterbenz), |f| <= 0.5
    double p =            1.0178086009239697e-7;
    p = fma(p, f, 1.3215486790144305e-6);
    p = fma(p, f, 1.5252733804059838e-5);
    p = fma(p, f, 1.5403530393381606e-4);
    p = fma(p, f, 1.3333558146428443e-3);
    p = fma(p, f, 9.6181291076284772e-3);
    p = fma(p, f, 5.5504108664821580e-2);
    p = fma(p, f, 2.4022650695910071e-1);
    p = fma(p, f, 6.9314718055994531e-1);
    p = fma(p, f, 1.0);
    double E  = ldexp(p, (int)n);        // exp(2|x|), >= 1
    double D  = E + 1.0;                 // [2, 2.4e17], no cancellation
    double r0 = (double)__builtin_amdgcn_rcpf((float)D);   // ~1e-7 rel
    double r1 = r0 * fma(-D, r0, 2.0);                     // ~1e-14 rel
    double q0 = 2.0 * r1;
    double q  = fma(r1, fma(-D, q0, 2.0), q0);             // 2/D to ~1 ulp
    double t  = 1.0 - q;
    return copysign(t, x);
}

__device__ __forceinline__ void store_softmax(float* __restrict__ out, size_t base,
                                              float a, float b, float c) {
    float m  = fmaxf(a, fmaxf(b, c));
    float e0 = expf(a - m);
    float e1 = expf(b - m);
    float e2 = expf(c - m);
    float s  = e0 + e1 + e2;
    out[base + 0] = e0 / s;
    out[base + 1] = e1 / s;
    out[base + 2] = e2 / s;
}

// Weights are fp64 in ws; W2 pre-transposed to [128][64].
__device__ __forceinline__ void mlp_eval(
    double zs, double zi, double zr, double be, double ga,
    const double* __restrict__ W1, const double* __restrict__ b1,
    const double* __restrict__ W2, const double* __restrict__ b2,
    const double* __restrict__ W3, const double* __restrict__ b3,
    const double* __restrict__ W4, const double* __restrict__ b4,
    double& d0, double& d1, double& d2)
{
    double h1[64];
    // layer 1: 5 -> 64 (fully unrolled: h1[] must stay in registers)
    #pragma unroll
    for (int j = 0; j < 64; ++j) {
        double t = b1[j];
        t = fma(W1[0 * 64 + j], zs, t);
        t = fma(W1[1 * 64 + j], zi, t);
        t = fma(W1[2 * 64 + j], zr, t);
        t = fma(W1[3 * 64 + j], be, t);
        t = fma(W1[4 * 64 + j], ga, t);
        h1[j] = tanh64(t);
    }

    // layers 2+3 fused: 64 -> 128 -> 64
    double acc[64];
    #pragma unroll
    for (int j = 0; j < 64; ++j) acc[j] = b3[j];

    #pragma unroll 2
    for (int k = 0; k < 128; ++k) {
        const double* w2k = W2 + (size_t)k * 64;   // contiguous row of W2^T
        // 4 independent partial chains: issue-bound, not latency-bound
        double t0 = b2[k], t1 = 0.0, t2 = 0.0, t3 = 0.0;
        #pragma unroll
        for (int i = 0; i < 64; i += 4) {
            t0 = fma(w2k[i + 0], h1[i + 0], t0);
            t1 = fma(w2k[i + 1], h1[i + 1], t1);
            t2 = fma(w2k[i + 2], h1[i + 2], t2);
            t3 = fma(w2k[i + 3], h1[i + 3], t3);
        }
        double h = tanh64((t0 + t1) + (t2 + t3));
        const double* w3k = W3 + (size_t)k * 64;
        #pragma unroll
        for (int j = 0; j < 64; ++j) acc[j] = fma(w3k[j], h, acc[j]);
    }

    // layer 4: 64 -> 3 (fully unrolled: acc[] in registers)
    double e0 = b4[0], e1 = b4[1], e2 = b4[2];
    #pragma unroll
    for (int j = 0; j < 64; ++j) {
        double h = tanh64(acc[j]);
        e0 = fma(W4[j * 3 + 0], h, e0);
        e1 = fma(W4[j * 3 + 1], h, e1);
        e2 = fma(W4[j * 3 + 2], h, e2);
    }
    d0 = e0; d1 = e1; d2 = e2;
}

__global__ __launch_bounds__(256, 1) void sir_rk4_kernel(
    const float* __restrict__ y0,   const float* __restrict__ tspan,
    const float* __restrict__ beta, const float* __restrict__ gamma,
    const double* __restrict__ W1,  const double* __restrict__ b1,
    const double* __restrict__ W2,  const double* __restrict__ b2,
    const double* __restrict__ W3,  const double* __restrict__ b3,
    const double* __restrict__ W4,  const double* __restrict__ b4,
    float* __restrict__ out, int B, int T)
{
    int b = blockIdx.x * blockDim.x + threadIdx.x;
    if (b >= B) return;

    double ys = (double)y0[b * 3 + 0];
    double yi = (double)y0[b * 3 + 1];
    double yr = (double)y0[b * 3 + 2];
    double be = (double)beta[b];
    double ga = (double)gamma[b];

    store_softmax(out, (size_t)b * 3, (float)ys, (float)yi, (float)yr);

    #pragma unroll 1
    for (int t = 0; t < T - 1; ++t) {
        double dt = (double)tspan[t + 1] - (double)tspan[t];

        double ks0 = 0.0, ks1 = 0.0, ks2 = 0.0;
        double zs = ys, zi = yi, zr = yr;

        #pragma unroll 1
        for (int st = 0; st < 4; ++st) {
            double d0, d1, d2;
            mlp_eval(zs, zi, zr, be, ga,
                     W1, b1, W2, b2, W3, b3, W4, b4, d0, d1, d2);
            double w = (st == 1 || st == 2) ? 2.0 : 1.0;
            ks0 = fma(w, d0, ks0);
            ks1 = fma(w, d1, ks1);
            ks2 = fma(w, d2, ks2);
            double a = (st < 2) ? 0.5 * dt : dt;
            zs = fma(a, d0, ys);
            zi = fma(a, d1, yi);
            zr = fma(a, d2, yr);
        }

        double c = dt * (1.0 / 6.0);
        ys = fma(c, ks0, ys);
        yi = fma(c, ks1, yi);
        yr = fma(c, ks2, yr);

        store_softmax(out, ((size_t)(t + 1) * B + b) * 3, (float)ys, (float)yi, (float)yr);
    }
}

// widen all params to fp64 in ws; W2 transposed to [128][64]
__global__ void stage_params_kernel(
    const float* __restrict__ W1, const float* __restrict__ b1,
    const float* __restrict__ W2, const float* __restrict__ b2,
    const float* __restrict__ W3, const float* __restrict__ b3,
    const float* __restrict__ W4, const float* __restrict__ b4,
    double* __restrict__ P)
{
    int idx = blockIdx.x * blockDim.x + threadIdx.x;
    if (idx >= NTOT) return;
    float v;
    if (idx < oB1)       v = W1[idx - oW1];
    else if (idx < oW2T) v = b1[idx - oB1];
    else if (idx < oB2)  { int u = idx - oW2T; int k = u / 64; int i = u % 64; v = W2[i * 128 + k]; }
    else if (idx < oW3)  v = b2[idx - oB2];
    else if (idx < oB3)  v = W3[idx - oW3];
    else if (idx < oW4)  v = b3[idx - oB3];
    else if (idx < oB4)  v = W4[idx - oW4];
    else                 v = b4[idx - oB4];
    P[idx] = (double)v;
}

// fp32 fallback (only if ws is too small — not expected)
__device__ __forceinline__ float fast_tanhf(float x) {
    float e = __builtin_amdgcn_exp2f(x * 2.885390081777927f);
    return 1.0f - 2.0f * __builtin_amdgcn_rcpf(e + 1.0f);
}
__global__ __launch_bounds__(256, 1) void sir_rk4_fallback(
    const float* __restrict__ y0,   const float* __restrict__ tspan,
    const float* __restrict__ beta, const float* __restrict__ gamma,
    const float* __restrict__ W1,   const float* __restrict__ b1,
    const float* __restrict__ W2,   const float* __restrict__ b2,
    const float* __restrict__ W3,   const float* __restrict__ b3,
    const float* __restrict__ W4,   const float* __restrict__ b4,
    float* __restrict__ out, int B, int T)
{
    int b = blockIdx.x * blockDim.x + threadIdx.x;
    if (b >= B) return;
    float ys = y0[b * 3 + 0], yi = y0[b * 3 + 1], yr = y0[b * 3 + 2];
    float be = beta[b], ga = gamma[b];
    store_softmax(out, (size_t)b * 3, ys, yi, yr);
    for (int t = 0; t < T - 1; ++t) {
        float dt = tspan[t + 1] - tspan[t];
        float ks0 = 0.f, ks1 = 0.f, ks2 = 0.f, zs = ys, zi = yi, zr = yr;
        for (int st = 0; st < 4; ++st) {
            float h1[64], acc[64];
            #pragma unroll
            for (int j = 0; j < 64; ++j) {
                float t0 = b1[j];
                t0 = fmaf(W1[0*64+j], zs, t0); t0 = fmaf(W1[1*64+j], zi, t0);
                t0 = fmaf(W1[2*64+j], zr, t0); t0 = fmaf(W1[3*64+j], be, t0);
                t0 = fmaf(W1[4*64+j], ga, t0);
                h1[j] = fast_tanhf(t0);
            }
            #pragma unroll
            for (int j = 0; j < 64; ++j) acc[j] = b3[j];
            #pragma unroll 1
            for (int k = 0; k < 128; ++k) {
                float t0 = b2[k];
                #pragma unroll
                for (int i = 0; i < 64; ++i) t0 = fmaf(W2[i * 128 + k], h1[i], t0);
                t0 = fast_tanhf(t0);
                #pragma unroll
                for (int j = 0; j < 64; ++j) acc[j] = fmaf(W3[k * 64 + j], t0, acc[j]);
            }
            float d0 = b4[0], d1 = b4[1], d2 = b4[2];
            #pragma unroll
            for (int j = 0; j < 64; ++j) {
                float h = fast_tanhf(acc[j]);
                d0 = fmaf(W4[j*3+0], h, d0); d1 = fmaf(W4[j*3+1], h, d1); d2 = fmaf(W4[j*3+2], h, d2);
            }
            float w = (st == 1 || st == 2) ? 2.0f : 1.0f;
            ks0 = fmaf(w, d0, ks0); ks1 = fmaf(w, d1, ks1); ks2 = fmaf(w, d2, ks2);
            float a = (st < 2) ? 0.5f * dt : dt;
            zs = fmaf(a, d0, ys); zi = fmaf(a, d1, yi); zr = fmaf(a, d2, yr);
        }
        float c = dt * (1.0f / 6.0f);
        ys = fmaf(c, ks0, ys); yi = fmaf(c, ks1, yi); yr = fmaf(c, ks2, yr);
        store_softmax(out, ((size_t)(t + 1) * B + b) * 3, ys, yi, yr);
    }
}

extern "C" void kernel_launch(void* const* d_in, const int* in_sizes, int n_in,
                              void* d_out, int out_size, void* d_ws, size_t ws_size,
                              hipStream_t stream) {
    const float* y0    = (const float*)d_in[0];
    const float* tspan = (const float*)d_in[1];
    const float* beta  = (const float*)d_in[2];
    const float* gamma = (const float*)d_in[3];
    const float* W1    = (const float*)d_in[4];
    const float* b1    = (const float*)d_in[5];
    const float* W2    = (const float*)d_in[6];
    const float* b2    = (const float*)d_in[7];
    const float* W3    = (const float*)d_in[8];
    const float* b3    = (const float*)d_in[9];
    const float* W4    = (const float*)d_in[10];
    const float* b4    = (const float*)d_in[11];

    int B = in_sizes[0] / 3;
    int T = in_sizes[1];
    float* out = (float*)d_out;

    int blocks = (B + 255) / 256;

    if (ws_size >= (size_t)NTOT * sizeof(double)) {
        double* P = (double*)d_ws;
        stage_params_kernel<<<(NTOT + 255) / 256, 256, 0, stream>>>(
            W1, b1, W2, b2, W3, b3, W4, b4, P);
        sir_rk4_kernel<<<blocks, 256, 0, stream>>>(
            y0, tspan, beta, gamma,
            P + oW1, P + oB1, P + oW2T, P + oB2,
            P + oW3, P + oB3, P + oW4,  P + oB4, out, B, T);
    } else {
        sir_rk4_fallback<<<blocks, 256, 0, stream>>>(
            y0, tspan, beta, gamma, W1, b1, W2, b2, W3, b3, W4, b4, out, B, T);
    }
}